// Round 19
// baseline (79.040 us; speedup 1.0000x reference)
//
#include <hip/hip_runtime.h>
#include <hip/hip_bf16.h>
#include <hip/hip_fp16.h>

#define NEG_SLOPE 0.2f
#define BUCK 128         // nodes per bucket
#define BSTRIDE 4096     // record slots per bucket (mean ~2176)
#define SRCM 0x1FFFFFFu  // low 25 bits = src
#define SCH 1024         // edges per scatter block (4 per thread, in registers)

__device__ __forceinline__ float lrelu(float x) {
    return x > 0.f ? x : NEG_SLOPE * x;
}

// ================= front: layer-1 transform | precompute + gcur init =================
__global__ __launch_bounds__(256)
void front_kernel(const float* __restrict__ x,
                  const float* __restrict__ W1,
                  const float* __restrict__ a1s, const float* __restrict__ a1d,
                  __half* __restrict__ h, float* __restrict__ as, float* __restrict__ ad,
                  int n, int tb,
                  const float* __restrict__ W2,
                  const float* __restrict__ a2s, const float* __restrict__ a2d,
                  const float* __restrict__ b2,
                  const float* __restrict__ Wl, const float* __restrict__ bl,
                  float* __restrict__ va, float* __restrict__ vd,
                  float* __restrict__ Wc, float* __restrict__ bc,
                  int* __restrict__ gcur, int nbuck) {
    const int bid = blockIdx.x;
    if (bid < tb) {
        constexpr int F_IN = 11, C_OUT = 16;
        __shared__ float sW[F_IN * C_OUT];
        __shared__ float sAs[C_OUT];
        __shared__ float sAd[C_OUT];
        for (int i = threadIdx.x; i < F_IN * C_OUT; i += 256) sW[i] = W1[i];
        if (threadIdx.x < C_OUT) { sAs[threadIdx.x] = a1s[threadIdx.x]; sAd[threadIdx.x] = a1d[threadIdx.x]; }
        __syncthreads();
        int i = bid * 256 + threadIdx.x;
        if (i >= n) return;
        float xin[F_IN];
#pragma unroll
        for (int f = 0; f < F_IN; ++f) xin[f] = x[(size_t)i * F_IN + f];
        float r[C_OUT];
        float s_acc = 0.f, d_acc = 0.f;
#pragma unroll
        for (int c = 0; c < C_OUT; ++c) {
            float acc = 0.f;
#pragma unroll
            for (int f = 0; f < F_IN; ++f) acc = fmaf(xin[f], sW[f * C_OUT + c], acc);
            r[c] = acc;
            s_acc = fmaf(acc, sAs[c], s_acc);
            d_acc = fmaf(acc, sAd[c], d_acc);
        }
        unsigned int u[8];
#pragma unroll
        for (int k = 0; k < 8; ++k) {
            __half2 hh = __floats2half2_rn(r[2 * k], r[2 * k + 1]);
            u[k] = *reinterpret_cast<unsigned int*>(&hh);
        }
        uint4* hp = reinterpret_cast<uint4*>(&h[(size_t)i * 16]);
        hp[0] = make_uint4(u[0], u[1], u[2], u[3]);
        hp[1] = make_uint4(u[4], u[5], u[6], u[7]);
        as[i] = s_acc;
        ad[i] = d_acc;
    } else {
        int t = threadIdx.x;
        for (int i = t; i < nbuck; i += 256) gcur[i] = i * BSTRIDE;
        if (t < 16) {
            float s = 0.f, s2 = 0.f;
            for (int c = 0; c < 64; ++c) {
                float w = W2[t * 64 + c];
                s = fmaf(w, a2s[c], s);
                s2 = fmaf(w, a2d[c], s2);
            }
            va[t] = s; vd[t] = s2;
        }
        int i = t - 64;
        if (i >= 0 && i < 160) {
            int f = i / 10, k = i % 10;
            float s = 0.f;
            for (int c = 0; c < 64; ++c) s = fmaf(W2[f * 64 + c], Wl[c * 10 + k], s);
            Wc[i] = s;
        }
        int k2 = t - 240;
        if (k2 >= 0 && k2 < 10) {
            float s = bl[k2];
            for (int c = 0; c < 64; ++c) s = fmaf(b2[c], Wl[c * 10 + k2], s);
            bc[k2] = s;
        }
    }
}

// ===== fused scatter: ONE ei pass, 4 edges/thread in registers (831 blocks) =====
__global__ __launch_bounds__(256)
void scatter_kernel(const int* __restrict__ ei, int E, int ET,
                    int* __restrict__ gcur, uint2* __restrict__ pk, int nbuck,
                    const float* __restrict__ as1, const float* __restrict__ ad1) {
    __shared__ int lhist[512];
    for (int i = threadIdx.x; i < nbuck; i += 256) lhist[i] = 0;
    __syncthreads();
    const int tid = threadIdx.x;
    const int beg = blockIdx.x * SCH;

    int rs0, rs1, rs2, rs3;
    int rd0, rd1, rd2, rd3;
    const int e0 = beg + tid * 4;
    if (e0 + 3 < E) {
        const int4 s4 = *reinterpret_cast<const int4*>(&ei[e0]);
        const int4 d4 = *reinterpret_cast<const int4*>(&ei[E + e0]);
        rs0 = s4.x; rs1 = s4.y; rs2 = s4.z; rs3 = s4.w;
        rd0 = d4.x; rd1 = d4.y; rd2 = d4.z; rd3 = d4.w;
    } else {
        rs0 = rd0 = (e0 + 0 < ET) ? ((e0 + 0 < E) ? 0 : e0 + 0 - E) : -1;
        if (e0 + 0 < E) { rs0 = ei[e0 + 0]; rd0 = ei[E + e0 + 0]; }
        rs1 = rd1 = (e0 + 1 < ET) ? ((e0 + 1 < E) ? 0 : e0 + 1 - E) : -1;
        if (e0 + 1 < E) { rs1 = ei[e0 + 1]; rd1 = ei[E + e0 + 1]; }
        rs2 = rd2 = (e0 + 2 < ET) ? ((e0 + 2 < E) ? 0 : e0 + 2 - E) : -1;
        if (e0 + 2 < E) { rs2 = ei[e0 + 2]; rd2 = ei[E + e0 + 2]; }
        rs3 = rd3 = (e0 + 3 < ET) ? ((e0 + 3 < E) ? 0 : e0 + 3 - E) : -1;
        if (e0 + 3 < E) { rs3 = ei[e0 + 3]; rd3 = ei[E + e0 + 3]; }
    }

    if (rd0 >= 0) atomicAdd(&lhist[rd0 >> 7], 1);
    if (rd1 >= 0) atomicAdd(&lhist[rd1 >> 7], 1);
    if (rd2 >= 0) atomicAdd(&lhist[rd2 >> 7], 1);
    if (rd3 >= 0) atomicAdd(&lhist[rd3 >> 7], 1);
    __syncthreads();

    for (int i = threadIdx.x; i < nbuck; i += 256) {
        int c = lhist[i];
        lhist[i] = (c > 0) ? atomicAdd(&gcur[i], c) : 0;
    }
    __syncthreads();

#define EMIT(RS, RD)                                                                   \
    if (RD >= 0) {                                                                     \
        float w = __expf(lrelu(as1[RS] + ad1[RD]));                                    \
        int slot = atomicAdd(&lhist[RD >> 7], 1);                                      \
        pk[slot] = make_uint2(((unsigned int)(RD & 127) << 25) | (unsigned int)RS,     \
                              __float_as_uint(w));                                     \
    }
    EMIT(rs0, rd0) EMIT(rs1, rd1) EMIT(rs2, rd2) EMIT(rs3, rd3)
#undef EMIT
}

// ===== per-bucket counting sort: sbuf + 2B index permutation (41KB LDS) =====
__global__ __launch_bounds__(256)
void bucketsort_kernel(const uint2* __restrict__ pk,
                       const int* __restrict__ gcur,
                       uint2* __restrict__ cw,
                       int* __restrict__ row_beg, int* __restrict__ deg,
                       int n) {
    __shared__ __align__(16) uint2 sbuf[BSTRIDE];   // 32KB raw records
    __shared__ unsigned short sidx[BSTRIDE];        // 8KB sorted->raw index
    __shared__ int lcnt[BUCK];
    __shared__ int lofs[BUCK];
    const int tid = threadIdx.x;
    const int base = blockIdx.x * BUCK;
    const int beg = blockIdx.x * BSTRIDE;
    const int cnt = gcur[blockIdx.x] - beg;

    if (tid < BUCK) lcnt[tid] = 0;
    for (int i = tid * 2; i < cnt; i += 512) {
        if (i + 1 < cnt) {
            *reinterpret_cast<uint4*>(&sbuf[i]) = *reinterpret_cast<const uint4*>(&pk[beg + i]);
        } else {
            sbuf[i] = pk[beg + i];
        }
    }
    __syncthreads();
    for (int i = tid; i < cnt; i += 256)
        atomicAdd(&lcnt[sbuf[i].x >> 25], 1);
    __syncthreads();
    int v = 0;
    if (tid < BUCK) { v = lcnt[tid]; lofs[tid] = v; }
    __syncthreads();
    for (int off = 1; off < BUCK; off <<= 1) {
        int u = 0;
        if (tid < BUCK && tid >= off) u = lofs[tid - off];
        __syncthreads();
        if (tid < BUCK && tid >= off) lofs[tid] += u;
        __syncthreads();
    }
    if (tid < BUCK) {
        int excl = lofs[tid] - v;
        if (base + tid < n) {
            row_beg[base + tid] = beg + excl;
            deg[base + tid] = v;
        }
        lcnt[tid] = excl;
    }
    __syncthreads();
    for (int i = tid; i < cnt; i += 256) {
        int d = (int)(sbuf[i].x >> 25);
        int slot = atomicAdd(&lcnt[d], 1);
        sidx[slot] = (unsigned short)i;
    }
    __syncthreads();
    // coalesced write-out via LDS index gather
    for (int j = tid; j < cnt; j += 256) cw[beg + j] = sbuf[sidx[j]];
}

// ===== layer-1 agg: staged weights -> pure streaming; LPR=4/EPW=4 =====
__global__ void gat_agg1_kernel(const int* __restrict__ row_beg,
                                const int* __restrict__ deg,
                                const uint2* __restrict__ cw,
                                const __half* __restrict__ h,    // N x 16 fp16
                                const float* __restrict__ b1,
                                const float* __restrict__ va,
                                const float* __restrict__ vd,
                                __half* __restrict__ X1r,        // N x 16 fp16 (relu'd)
                                float* __restrict__ as2,
                                float* __restrict__ ad2, int n) {
    __shared__ float sb1[16], sva[16], svd[16];
    if (threadIdx.x < 16) {
        sb1[threadIdx.x] = b1[threadIdx.x];
        sva[threadIdx.x] = va[threadIdx.x];
        svd[threadIdx.x] = vd[threadIdx.x];
    }
    __syncthreads();
    int node = (blockIdx.x * blockDim.x + threadIdx.x) >> 4;
    int sl = threadIdx.x & 15;
    if (node >= n) return;
    int beg = row_beg[node];
    int end = beg + deg[node];

    const int eq = sl >> 2;
    const int cl = sl & 3;
    float lsum = 0.f;
    float4 acc = {0.f, 0.f, 0.f, 0.f};
    for (int chunk = beg; chunk < end; chunk += 16) {
        int e = chunk + sl;
        float wv = 0.f; int sv = 0;
        if (e < end) {
            uint2 rec = cw[e];               // contiguous 8B load, no gather
            sv = (int)(rec.x & SRCM);
            wv = __uint_as_float(rec.y);
            lsum += wv;
        }
        const int nch = min(16, end - chunk);
        const int T = (nch + 3) >> 2;
        for (int t = 0; t < T; ++t) {
            int j = t * 4 + eq;
            float wj = __shfl(wv, j, 16);
            int   sj = __shfl(sv, j, 16);
            if (j < nch) {
                uint2 hv2 = *reinterpret_cast<const uint2*>(&h[(size_t)sj * 16 + cl * 4]);
                float2 f01 = __half22float2(*reinterpret_cast<__half2*>(&hv2.x));
                float2 f23 = __half22float2(*reinterpret_cast<__half2*>(&hv2.y));
                acc.x = fmaf(wj, f01.x, acc.x);
                acc.y = fmaf(wj, f01.y, acc.y);
                acc.z = fmaf(wj, f23.x, acc.z);
                acc.w = fmaf(wj, f23.y, acc.w);
            }
        }
    }
#pragma unroll
    for (int k = 1; k < 16; k <<= 1) lsum += __shfl_xor(lsum, k, 16);
#pragma unroll
    for (int k = 4; k < 16; k <<= 1) {
        acc.x += __shfl_xor(acc.x, k, 16);
        acc.y += __shfl_xor(acc.y, k, 16);
        acc.z += __shfl_xor(acc.z, k, 16);
        acc.w += __shfl_xor(acc.w, k, 16);
    }
    float inv = 1.f / lsum;
    float x0 = fmaxf(fmaf(acc.x, inv, sb1[cl * 4 + 0]), 0.f);
    float x1 = fmaxf(fmaf(acc.y, inv, sb1[cl * 4 + 1]), 0.f);
    float x2 = fmaxf(fmaf(acc.z, inv, sb1[cl * 4 + 2]), 0.f);
    float x3 = fmaxf(fmaf(acc.w, inv, sb1[cl * 4 + 3]), 0.f);
    if (eq == 0) {
        __half2 p01 = __floats2half2_rn(x0, x1);
        __half2 p23 = __floats2half2_rn(x2, x3);
        uint2 o = make_uint2(*reinterpret_cast<unsigned int*>(&p01),
                             *reinterpret_cast<unsigned int*>(&p23));
        *reinterpret_cast<uint2*>(&X1r[(size_t)node * 16 + cl * 4]) = o;
    }
    float p = x0 * sva[cl * 4] + x1 * sva[cl * 4 + 1] + x2 * sva[cl * 4 + 2] + x3 * sva[cl * 4 + 3];
    float q = x0 * svd[cl * 4] + x1 * svd[cl * 4 + 1] + x2 * svd[cl * 4 + 2] + x3 * svd[cl * 4 + 3];
    p += __shfl_xor(p, 1, 16); p += __shfl_xor(p, 2, 16);
    q += __shfl_xor(q, 1, 16); q += __shfl_xor(q, 2, 16);
    if (sl == 0) { as2[node] = p; ad2[node] = q; }
}

// ===== layer-2 agg: inline exp + fp16 X1r gather (LPR=4) + folded linear =====
__global__ void gat_agg2_kernel(const int* __restrict__ row_beg,
                                const int* __restrict__ deg,
                                const uint2* __restrict__ cw,
                                const float* __restrict__ as2,
                                const float* __restrict__ ad2,
                                const __half* __restrict__ X1r,  // N x 16 fp16
                                const float* __restrict__ Wc,    // 16 x 10
                                const float* __restrict__ bc,    // 10
                                float* __restrict__ out, int n) {
    __shared__ float sWc[160], sbc[10];
    for (int i = threadIdx.x; i < 160; i += blockDim.x) sWc[i] = Wc[i];
    if (threadIdx.x < 10) sbc[threadIdx.x] = bc[threadIdx.x];
    __syncthreads();
    int node = (blockIdx.x * blockDim.x + threadIdx.x) >> 4;
    int sl = threadIdx.x & 15;
    if (node >= n) return;
    int beg = row_beg[node];
    int end = beg + deg[node];
    float add = ad2[node];

    const int eq = sl >> 2;
    const int cl = sl & 3;
    float lsum = 0.f;
    float4 acc = {0.f, 0.f, 0.f, 0.f};
    for (int chunk = beg; chunk < end; chunk += 16) {
        int e = chunk + sl;
        float wv = 0.f; int sv = 0;
        if (e < end) {
            sv = (int)(cw[e].x & SRCM);
            wv = __expf(lrelu(as2[sv] + add));
            lsum += wv;
        }
        const int nch = min(16, end - chunk);
        const int T = (nch + 3) >> 2;
        for (int t = 0; t < T; ++t) {
            int j = t * 4 + eq;
            float wj = __shfl(wv, j, 16);
            int   sj = __shfl(sv, j, 16);
            if (j < nch) {
                uint2 hv2 = *reinterpret_cast<const uint2*>(&X1r[(size_t)sj * 16 + cl * 4]);
                float2 f01 = __half22float2(*reinterpret_cast<__half2*>(&hv2.x));
                float2 f23 = __half22float2(*reinterpret_cast<__half2*>(&hv2.y));
                acc.x = fmaf(wj, f01.x, acc.x);
                acc.y = fmaf(wj, f01.y, acc.y);
                acc.z = fmaf(wj, f23.x, acc.z);
                acc.w = fmaf(wj, f23.y, acc.w);
            }
        }
    }
#pragma unroll
    for (int k = 1; k < 16; k <<= 1) lsum += __shfl_xor(lsum, k, 16);
#pragma unroll
    for (int k = 4; k < 16; k <<= 1) {
        acc.x += __shfl_xor(acc.x, k, 16);
        acc.y += __shfl_xor(acc.y, k, 16);
        acc.z += __shfl_xor(acc.z, k, 16);
        acc.w += __shfl_xor(acc.w, k, 16);
    }
    float inv = 1.f / lsum;
    acc.x *= inv; acc.y *= inv; acc.z *= inv; acc.w *= inv;
    float p[10];
#pragma unroll
    for (int k = 0; k < 10; ++k) {
        p[k] = acc.x * sWc[(cl * 4 + 0) * 10 + k]
             + acc.y * sWc[(cl * 4 + 1) * 10 + k]
             + acc.z * sWc[(cl * 4 + 2) * 10 + k]
             + acc.w * sWc[(cl * 4 + 3) * 10 + k];
    }
#pragma unroll
    for (int k = 0; k < 10; ++k) {
        p[k] += __shfl_xor(p[k], 1, 16);
        p[k] += __shfl_xor(p[k], 2, 16);
    }
    if (sl < 10) {
        float v = p[0];
#pragma unroll
        for (int k = 1; k < 10; ++k) v = (sl == k) ? p[k] : v;
        out[(size_t)node * 10 + sl] = v + sbc[sl];
    }
}

extern "C" void kernel_launch(void* const* d_in, const int* in_sizes, int n_in,
                              void* d_out, int out_size, void* d_ws, size_t ws_size,
                              hipStream_t stream) {
    const float* x       = (const float*)d_in[0];
    const int*   ei      = (const int*)d_in[1];
    // d_in[2] = batch (unused)
    const float* W1      = (const float*)d_in[3];
    const float* a1_src  = (const float*)d_in[4];
    const float* a1_dst  = (const float*)d_in[5];
    const float* b1      = (const float*)d_in[6];
    const float* W2      = (const float*)d_in[7];
    const float* a2_src  = (const float*)d_in[8];
    const float* a2_dst  = (const float*)d_in[9];
    const float* b2      = (const float*)d_in[10];
    const float* Wl      = (const float*)d_in[11];
    const float* bl      = (const float*)d_in[12];
    float* out = (float*)d_out;

    const int N = in_sizes[2];        // 50000
    const int E = in_sizes[1] / 2;    // 800000
    const int ET = E + N;             // with self-loops

    const int B = 256;
    auto cdiv = [](int a, int b) { return (a + b - 1) / b; };

    const int NBUCK = cdiv(N, BUCK);             // 391 buckets of 128 nodes
    const int NBLK  = cdiv(ET, SCH);             // scatter blocks (831)
    const int TB    = cdiv(N, B);                // transform blocks

    char* ws = (char*)d_ws;
    size_t off = 0;
    auto alloc = [&](size_t bytes) {
        char* p = ws + off;
        off = (off + bytes + 255) & ~(size_t)255;
        return p;
    };
    __half*       h1   = (__half*)alloc((size_t)N * 16 * 2);
    __half*       X1r  = (__half*)alloc((size_t)N * 16 * 2);
    float*        as1  = (float*)alloc((size_t)N * 4);
    float*        ad1  = (float*)alloc((size_t)N * 4);
    float*        as2  = (float*)alloc((size_t)N * 4);
    float*        ad2  = (float*)alloc((size_t)N * 4);
    int*          rowb = (int*)alloc((size_t)N * 4);
    int*          degb = (int*)alloc((size_t)N * 4);
    uint2*        cw   = (uint2*)alloc((size_t)NBUCK * BSTRIDE * 8);
    uint2*        pk   = (uint2*)alloc((size_t)NBUCK * BSTRIDE * 8);
    int*          gcur = (int*)alloc((size_t)NBUCK * 4);
    float*        va   = (float*)alloc(16 * 4);
    float*        vd   = (float*)alloc(16 * 4);
    float*        Wc   = (float*)alloc(160 * 4);
    float*        bc   = (float*)alloc(10 * 4);
    (void)ws_size;

    // ===== front: layer-1 transform | weight folding + gcur init =====
    front_kernel<<<TB + 1, B, 0, stream>>>(
        x, W1, a1_src, a1_dst, h1, as1, ad1, N, TB,
        W2, a2_src, a2_dst, b2, Wl, bl, va, vd, Wc, bc, gcur, NBUCK);

    // ===== fused single-pass hist + reserve + w1 + scatter (831 blocks) =====
    scatter_kernel<<<NBLK, B, 0, stream>>>(ei, E, ET, gcur, pk, NBUCK, as1, ad1);

    // ===== per-bucket LDS counting sort (sidx permutation, 41KB LDS) =====
    bucketsort_kernel<<<NBUCK, 256, 0, stream>>>(pk, gcur, cw, rowb, degb, N);

    // ===== layer 1 agg (streaming staged weights) =====
    gat_agg1_kernel<<<cdiv(N * 16, B), B, 0, stream>>>(rowb, degb, cw, h1, b1, va, vd, X1r, as2, ad2, N);

    // ===== layer 2 agg + folded linear =====
    gat_agg2_kernel<<<cdiv(N * 16, B), B, 0, stream>>>(rowb, degb, cw, as2, ad2, X1r, Wc, bc, out, N);
}

// Round 20
// 67.389 us; speedup vs baseline: 1.1729x; 1.1729x over previous
//
#include <hip/hip_runtime.h>
#include <hip/hip_bf16.h>
#include <hip/hip_fp16.h>

#define NEG_SLOPE 0.2f
#define BUCK 128         // nodes per bucket
#define BSTRIDE 4096     // record slots per bucket (mean ~2176, +41 sigma headroom)
#define SRCM 0x1FFFFFFu  // low 25 bits = src
#define SCH 2048         // edges per scatter block (8 per thread, in registers)

__device__ __forceinline__ float lrelu(float x) {
    return x > 0.f ? x : NEG_SLOPE * x;
}

// ================= front: layer-1 transform | precompute + gcur init =================
__global__ __launch_bounds__(256)
void front_kernel(const float* __restrict__ x,
                  const float* __restrict__ W1,
                  const float* __restrict__ a1s, const float* __restrict__ a1d,
                  __half* __restrict__ h, float* __restrict__ as, float* __restrict__ ad,
                  int n, int tb,
                  const float* __restrict__ W2,
                  const float* __restrict__ a2s, const float* __restrict__ a2d,
                  const float* __restrict__ b2,
                  const float* __restrict__ Wl, const float* __restrict__ bl,
                  float* __restrict__ va, float* __restrict__ vd,
                  float* __restrict__ Wc, float* __restrict__ bc,
                  int* __restrict__ gcur, int nbuck) {
    const int bid = blockIdx.x;
    if (bid < tb) {
        constexpr int F_IN = 11, C_OUT = 16;
        __shared__ float sW[F_IN * C_OUT];
        __shared__ float sAs[C_OUT];
        __shared__ float sAd[C_OUT];
        __shared__ float sx[256 * F_IN];     // 11264B staged rows
        for (int i = threadIdx.x; i < F_IN * C_OUT; i += 256) sW[i] = W1[i];
        if (threadIdx.x < C_OUT) { sAs[threadIdx.x] = a1s[threadIdx.x]; sAd[threadIdx.x] = a1d[threadIdx.x]; }
        // coalesced staging of this block's 256 rows of x
        const int rbase = bid * 256;
        const int fbase = rbase * F_IN;
        if (rbase + 256 <= n) {
            const float4* src4 = reinterpret_cast<const float4*>(x + fbase);  // 16B-aligned (11264*bid)
            float4* dst4 = reinterpret_cast<float4*>(sx);
            for (int i = threadIdx.x; i < (256 * F_IN) / 4; i += 256) dst4[i] = src4[i];
        } else {
            const int nflt = (n - rbase) * F_IN;
            for (int i = threadIdx.x; i < nflt; i += 256) sx[i] = x[fbase + i];
        }
        __syncthreads();
        int i = rbase + threadIdx.x;
        if (i >= n) return;
        float xin[F_IN];
#pragma unroll
        for (int f = 0; f < F_IN; ++f) xin[f] = sx[threadIdx.x * F_IN + f];
        float r[C_OUT];
        float s_acc = 0.f, d_acc = 0.f;
#pragma unroll
        for (int c = 0; c < C_OUT; ++c) {
            float acc = 0.f;
#pragma unroll
            for (int f = 0; f < F_IN; ++f) acc = fmaf(xin[f], sW[f * C_OUT + c], acc);
            r[c] = acc;
            s_acc = fmaf(acc, sAs[c], s_acc);
            d_acc = fmaf(acc, sAd[c], d_acc);
        }
        unsigned int u[8];
#pragma unroll
        for (int k = 0; k < 8; ++k) {
            __half2 hh = __floats2half2_rn(r[2 * k], r[2 * k + 1]);
            u[k] = *reinterpret_cast<unsigned int*>(&hh);
        }
        uint4* hp = reinterpret_cast<uint4*>(&h[(size_t)i * 16]);
        hp[0] = make_uint4(u[0], u[1], u[2], u[3]);
        hp[1] = make_uint4(u[4], u[5], u[6], u[7]);
        as[i] = s_acc;
        ad[i] = d_acc;
    } else {
        int t = threadIdx.x;
        for (int i = t; i < nbuck; i += 256) gcur[i] = i * BSTRIDE;
        if (t < 16) {
            float s = 0.f, s2 = 0.f;
            for (int c = 0; c < 64; ++c) {
                float w = W2[t * 64 + c];
                s = fmaf(w, a2s[c], s);
                s2 = fmaf(w, a2d[c], s2);
            }
            va[t] = s; vd[t] = s2;
        }
        int i = t - 64;
        if (i >= 0 && i < 160) {
            int f = i / 10, k = i % 10;
            float s = 0.f;
            for (int c = 0; c < 64; ++c) s = fmaf(W2[f * 64 + c], Wl[c * 10 + k], s);
            Wc[i] = s;
        }
        int k2 = t - 240;
        if (k2 >= 0 && k2 < 10) {
            float s = bl[k2];
            for (int c = 0; c < 64; ++c) s = fmaf(b2[c], Wl[c * 10 + k2], s);
            bc[k2] = s;
        }
    }
}

// ===== fused scatter: ONE ei pass, 8 edges/thread in registers =====
__global__ __launch_bounds__(256)
void scatter_kernel(const int* __restrict__ ei, int E, int ET,
                    int* __restrict__ gcur, uint2* __restrict__ pk, int nbuck,
                    const float* __restrict__ as1, const float* __restrict__ ad1) {
    __shared__ int lhist[512];
    for (int i = threadIdx.x; i < nbuck; i += 256) lhist[i] = 0;
    __syncthreads();
    const int tid = threadIdx.x;
    const int beg = blockIdx.x * SCH;

    int rs0, rs1, rs2, rs3, rs4, rs5, rs6, rs7;
    int rd0, rd1, rd2, rd3, rd4, rd5, rd6, rd7;
    const int e0 = beg + tid * 4;
    const int e1 = e0 + 1024;
    if (e0 + 3 < E) {
        const int4 s4 = *reinterpret_cast<const int4*>(&ei[e0]);
        const int4 d4 = *reinterpret_cast<const int4*>(&ei[E + e0]);
        rs0 = s4.x; rs1 = s4.y; rs2 = s4.z; rs3 = s4.w;
        rd0 = d4.x; rd1 = d4.y; rd2 = d4.z; rd3 = d4.w;
    } else {
        rs0 = rd0 = (e0 + 0 < ET) ? ((e0 + 0 < E) ? 0 : e0 + 0 - E) : -1;
        if (e0 + 0 < E) { rs0 = ei[e0 + 0]; rd0 = ei[E + e0 + 0]; }
        rs1 = rd1 = (e0 + 1 < ET) ? ((e0 + 1 < E) ? 0 : e0 + 1 - E) : -1;
        if (e0 + 1 < E) { rs1 = ei[e0 + 1]; rd1 = ei[E + e0 + 1]; }
        rs2 = rd2 = (e0 + 2 < ET) ? ((e0 + 2 < E) ? 0 : e0 + 2 - E) : -1;
        if (e0 + 2 < E) { rs2 = ei[e0 + 2]; rd2 = ei[E + e0 + 2]; }
        rs3 = rd3 = (e0 + 3 < ET) ? ((e0 + 3 < E) ? 0 : e0 + 3 - E) : -1;
        if (e0 + 3 < E) { rs3 = ei[e0 + 3]; rd3 = ei[E + e0 + 3]; }
    }
    if (e1 + 3 < E) {
        const int4 s4 = *reinterpret_cast<const int4*>(&ei[e1]);
        const int4 d4 = *reinterpret_cast<const int4*>(&ei[E + e1]);
        rs4 = s4.x; rs5 = s4.y; rs6 = s4.z; rs7 = s4.w;
        rd4 = d4.x; rd5 = d4.y; rd6 = d4.z; rd7 = d4.w;
    } else {
        rs4 = rd4 = (e1 + 0 < ET) ? ((e1 + 0 < E) ? 0 : e1 + 0 - E) : -1;
        if (e1 + 0 < E) { rs4 = ei[e1 + 0]; rd4 = ei[E + e1 + 0]; }
        rs5 = rd5 = (e1 + 1 < ET) ? ((e1 + 1 < E) ? 0 : e1 + 1 - E) : -1;
        if (e1 + 1 < E) { rs5 = ei[e1 + 1]; rd5 = ei[E + e1 + 1]; }
        rs6 = rd6 = (e1 + 2 < ET) ? ((e1 + 2 < E) ? 0 : e1 + 2 - E) : -1;
        if (e1 + 2 < E) { rs6 = ei[e1 + 2]; rd6 = ei[E + e1 + 2]; }
        rs7 = rd7 = (e1 + 3 < ET) ? ((e1 + 3 < E) ? 0 : e1 + 3 - E) : -1;
        if (e1 + 3 < E) { rs7 = ei[e1 + 3]; rd7 = ei[E + e1 + 3]; }
    }

    if (rd0 >= 0) atomicAdd(&lhist[rd0 >> 7], 1);
    if (rd1 >= 0) atomicAdd(&lhist[rd1 >> 7], 1);
    if (rd2 >= 0) atomicAdd(&lhist[rd2 >> 7], 1);
    if (rd3 >= 0) atomicAdd(&lhist[rd3 >> 7], 1);
    if (rd4 >= 0) atomicAdd(&lhist[rd4 >> 7], 1);
    if (rd5 >= 0) atomicAdd(&lhist[rd5 >> 7], 1);
    if (rd6 >= 0) atomicAdd(&lhist[rd6 >> 7], 1);
    if (rd7 >= 0) atomicAdd(&lhist[rd7 >> 7], 1);
    __syncthreads();

    for (int i = threadIdx.x; i < nbuck; i += 256) {
        int c = lhist[i];
        lhist[i] = (c > 0) ? atomicAdd(&gcur[i], c) : 0;
    }
    __syncthreads();

#define EMIT(RS, RD)                                                                   \
    if (RD >= 0) {                                                                     \
        float w = __expf(lrelu(as1[RS] + ad1[RD]));                                    \
        int slot = atomicAdd(&lhist[RD >> 7], 1);                                      \
        pk[slot] = make_uint2(((unsigned int)(RD & 127) << 25) | (unsigned int)RS,     \
                              __float_as_uint(w));                                     \
    }
    EMIT(rs0, rd0) EMIT(rs1, rd1) EMIT(rs2, rd2) EMIT(rs3, rd3)
    EMIT(rs4, rd4) EMIT(rs5, rd5) EMIT(rs6, rd6) EMIT(rs7, rd7)
#undef EMIT
}

// ===== per-bucket counting sort, single pk pass, all staging in LDS;
// coalesced uint4 write-out of sorted records + row_beg/deg. =====
__global__ __launch_bounds__(256)
void bucketsort_kernel(const uint2* __restrict__ pk,
                       const int* __restrict__ gcur,
                       uint2* __restrict__ cw,
                       int* __restrict__ row_beg, int* __restrict__ deg,
                       int n) {
    __shared__ uint2 sbuf[BSTRIDE];   // 32KB: raw records
    __shared__ uint2 dbuf[BSTRIDE];   // 32KB: node-sorted records
    __shared__ int lcnt[BUCK];
    __shared__ int lofs[BUCK];
    const int tid = threadIdx.x;
    const int base = blockIdx.x * BUCK;
    const int beg = blockIdx.x * BSTRIDE;
    const int cnt = gcur[blockIdx.x] - beg;

    if (tid < BUCK) lcnt[tid] = 0;
    for (int i = tid * 2; i < cnt; i += 512) {
        if (i + 1 < cnt) {
            *reinterpret_cast<uint4*>(&sbuf[i]) = *reinterpret_cast<const uint4*>(&pk[beg + i]);
        } else {
            sbuf[i] = pk[beg + i];
        }
    }
    __syncthreads();
    for (int i = tid; i < cnt; i += 256)
        atomicAdd(&lcnt[sbuf[i].x >> 25], 1);
    __syncthreads();
    int v = 0;
    if (tid < BUCK) { v = lcnt[tid]; lofs[tid] = v; }
    __syncthreads();
    for (int off = 1; off < BUCK; off <<= 1) {
        int u = 0;
        if (tid < BUCK && tid >= off) u = lofs[tid - off];
        __syncthreads();
        if (tid < BUCK && tid >= off) lofs[tid] += u;
        __syncthreads();
    }
    if (tid < BUCK) {
        int excl = lofs[tid] - v;
        if (base + tid < n) {
            row_beg[base + tid] = beg + excl;
            deg[base + tid] = v;
        }
        lcnt[tid] = excl;
    }
    __syncthreads();
    for (int i = tid; i < cnt; i += 256) {
        uint2 rec = sbuf[i];
        int slot = atomicAdd(&lcnt[rec.x >> 25], 1);
        dbuf[slot] = rec;
    }
    __syncthreads();
    for (int i = tid * 2; i < cnt; i += 512) {
        if (i + 1 < cnt) {
            *reinterpret_cast<uint4*>(&cw[beg + i]) = *reinterpret_cast<uint4*>(&dbuf[i]);
        } else {
            cw[beg + i] = dbuf[i];
        }
    }
}

// ===== layer-1 agg: staged weights -> pure streaming; LPR=4/EPW=4 =====
__global__ void gat_agg1_kernel(const int* __restrict__ row_beg,
                                const int* __restrict__ deg,
                                const uint2* __restrict__ cw,
                                const __half* __restrict__ h,    // N x 16 fp16
                                const float* __restrict__ b1,
                                const float* __restrict__ va,
                                const float* __restrict__ vd,
                                __half* __restrict__ X1r,        // N x 16 fp16 (relu'd)
                                float* __restrict__ as2,
                                float* __restrict__ ad2, int n) {
    __shared__ float sb1[16], sva[16], svd[16];
    if (threadIdx.x < 16) {
        sb1[threadIdx.x] = b1[threadIdx.x];
        sva[threadIdx.x] = va[threadIdx.x];
        svd[threadIdx.x] = vd[threadIdx.x];
    }
    __syncthreads();
    int node = (blockIdx.x * blockDim.x + threadIdx.x) >> 4;
    int sl = threadIdx.x & 15;
    if (node >= n) return;
    int beg = row_beg[node];
    int end = beg + deg[node];

    const int eq = sl >> 2;
    const int cl = sl & 3;
    float lsum = 0.f;
    float4 acc = {0.f, 0.f, 0.f, 0.f};
    for (int chunk = beg; chunk < end; chunk += 16) {
        int e = chunk + sl;
        float wv = 0.f; int sv = 0;
        if (e < end) {
            uint2 rec = cw[e];               // contiguous 8B load, no gather
            sv = (int)(rec.x & SRCM);
            wv = __uint_as_float(rec.y);
            lsum += wv;
        }
        const int nch = min(16, end - chunk);
        const int T = (nch + 3) >> 2;
        for (int t = 0; t < T; ++t) {
            int j = t * 4 + eq;
            float wj = __shfl(wv, j, 16);
            int   sj = __shfl(sv, j, 16);
            if (j < nch) {
                uint2 hv2 = *reinterpret_cast<const uint2*>(&h[(size_t)sj * 16 + cl * 4]);
                float2 f01 = __half22float2(*reinterpret_cast<__half2*>(&hv2.x));
                float2 f23 = __half22float2(*reinterpret_cast<__half2*>(&hv2.y));
                acc.x = fmaf(wj, f01.x, acc.x);
                acc.y = fmaf(wj, f01.y, acc.y);
                acc.z = fmaf(wj, f23.x, acc.z);
                acc.w = fmaf(wj, f23.y, acc.w);
            }
        }
    }
#pragma unroll
    for (int k = 1; k < 16; k <<= 1) lsum += __shfl_xor(lsum, k, 16);
#pragma unroll
    for (int k = 4; k < 16; k <<= 1) {
        acc.x += __shfl_xor(acc.x, k, 16);
        acc.y += __shfl_xor(acc.y, k, 16);
        acc.z += __shfl_xor(acc.z, k, 16);
        acc.w += __shfl_xor(acc.w, k, 16);
    }
    float inv = 1.f / lsum;
    float x0 = fmaxf(fmaf(acc.x, inv, sb1[cl * 4 + 0]), 0.f);
    float x1 = fmaxf(fmaf(acc.y, inv, sb1[cl * 4 + 1]), 0.f);
    float x2 = fmaxf(fmaf(acc.z, inv, sb1[cl * 4 + 2]), 0.f);
    float x3 = fmaxf(fmaf(acc.w, inv, sb1[cl * 4 + 3]), 0.f);
    if (eq == 0) {
        __half2 p01 = __floats2half2_rn(x0, x1);
        __half2 p23 = __floats2half2_rn(x2, x3);
        uint2 o = make_uint2(*reinterpret_cast<unsigned int*>(&p01),
                             *reinterpret_cast<unsigned int*>(&p23));
        *reinterpret_cast<uint2*>(&X1r[(size_t)node * 16 + cl * 4]) = o;
    }
    float p = x0 * sva[cl * 4] + x1 * sva[cl * 4 + 1] + x2 * sva[cl * 4 + 2] + x3 * sva[cl * 4 + 3];
    float q = x0 * svd[cl * 4] + x1 * svd[cl * 4 + 1] + x2 * svd[cl * 4 + 2] + x3 * svd[cl * 4 + 3];
    p += __shfl_xor(p, 1, 16); p += __shfl_xor(p, 2, 16);
    q += __shfl_xor(q, 1, 16); q += __shfl_xor(q, 2, 16);
    if (sl == 0) { as2[node] = p; ad2[node] = q; }
}

// ===== layer-2 agg: inline exp + fp16 X1r gather (LPR=4) + folded linear =====
__global__ void gat_agg2_kernel(const int* __restrict__ row_beg,
                                const int* __restrict__ deg,
                                const uint2* __restrict__ cw,
                                const float* __restrict__ as2,
                                const float* __restrict__ ad2,
                                const __half* __restrict__ X1r,  // N x 16 fp16
                                const float* __restrict__ Wc,    // 16 x 10
                                const float* __restrict__ bc,    // 10
                                float* __restrict__ out, int n) {
    __shared__ float sWc[160], sbc[10];
    for (int i = threadIdx.x; i < 160; i += blockDim.x) sWc[i] = Wc[i];
    if (threadIdx.x < 10) sbc[threadIdx.x] = bc[threadIdx.x];
    __syncthreads();
    int node = (blockIdx.x * blockDim.x + threadIdx.x) >> 4;
    int sl = threadIdx.x & 15;
    if (node >= n) return;
    int beg = row_beg[node];
    int end = beg + deg[node];
    float add = ad2[node];

    const int eq = sl >> 2;
    const int cl = sl & 3;
    float lsum = 0.f;
    float4 acc = {0.f, 0.f, 0.f, 0.f};
    for (int chunk = beg; chunk < end; chunk += 16) {
        int e = chunk + sl;
        float wv = 0.f; int sv = 0;
        if (e < end) {
            sv = (int)(cw[e].x & SRCM);
            wv = __expf(lrelu(as2[sv] + add));
            lsum += wv;
        }
        const int nch = min(16, end - chunk);
        const int T = (nch + 3) >> 2;
        for (int t = 0; t < T; ++t) {
            int j = t * 4 + eq;
            float wj = __shfl(wv, j, 16);
            int   sj = __shfl(sv, j, 16);
            if (j < nch) {
                uint2 hv2 = *reinterpret_cast<const uint2*>(&X1r[(size_t)sj * 16 + cl * 4]);
                float2 f01 = __half22float2(*reinterpret_cast<__half2*>(&hv2.x));
                float2 f23 = __half22float2(*reinterpret_cast<__half2*>(&hv2.y));
                acc.x = fmaf(wj, f01.x, acc.x);
                acc.y = fmaf(wj, f01.y, acc.y);
                acc.z = fmaf(wj, f23.x, acc.z);
                acc.w = fmaf(wj, f23.y, acc.w);
            }
        }
    }
#pragma unroll
    for (int k = 1; k < 16; k <<= 1) lsum += __shfl_xor(lsum, k, 16);
#pragma unroll
    for (int k = 4; k < 16; k <<= 1) {
        acc.x += __shfl_xor(acc.x, k, 16);
        acc.y += __shfl_xor(acc.y, k, 16);
        acc.z += __shfl_xor(acc.z, k, 16);
        acc.w += __shfl_xor(acc.w, k, 16);
    }
    float inv = 1.f / lsum;
    acc.x *= inv; acc.y *= inv; acc.z *= inv; acc.w *= inv;
    float p[10];
#pragma unroll
    for (int k = 0; k < 10; ++k) {
        p[k] = acc.x * sWc[(cl * 4 + 0) * 10 + k]
             + acc.y * sWc[(cl * 4 + 1) * 10 + k]
             + acc.z * sWc[(cl * 4 + 2) * 10 + k]
             + acc.w * sWc[(cl * 4 + 3) * 10 + k];
    }
#pragma unroll
    for (int k = 0; k < 10; ++k) {
        p[k] += __shfl_xor(p[k], 1, 16);
        p[k] += __shfl_xor(p[k], 2, 16);
    }
    if (sl < 10) {
        float v = p[0];
#pragma unroll
        for (int k = 1; k < 10; ++k) v = (sl == k) ? p[k] : v;
        out[(size_t)node * 10 + sl] = v + sbc[sl];
    }
}

extern "C" void kernel_launch(void* const* d_in, const int* in_sizes, int n_in,
                              void* d_out, int out_size, void* d_ws, size_t ws_size,
                              hipStream_t stream) {
    const float* x       = (const float*)d_in[0];
    const int*   ei      = (const int*)d_in[1];
    // d_in[2] = batch (unused)
    const float* W1      = (const float*)d_in[3];
    const float* a1_src  = (const float*)d_in[4];
    const float* a1_dst  = (const float*)d_in[5];
    const float* b1      = (const float*)d_in[6];
    const float* W2      = (const float*)d_in[7];
    const float* a2_src  = (const float*)d_in[8];
    const float* a2_dst  = (const float*)d_in[9];
    const float* b2      = (const float*)d_in[10];
    const float* Wl      = (const float*)d_in[11];
    const float* bl      = (const float*)d_in[12];
    float* out = (float*)d_out;

    const int N = in_sizes[2];        // 50000
    const int E = in_sizes[1] / 2;    // 800000
    const int ET = E + N;             // with self-loops

    const int B = 256;
    auto cdiv = [](int a, int b) { return (a + b - 1) / b; };

    const int NBUCK = cdiv(N, BUCK);             // 391 buckets of 128 nodes
    const int NBLK  = cdiv(ET, SCH);             // scatter blocks (416)
    const int TB    = cdiv(N, B);                // transform blocks

    char* ws = (char*)d_ws;
    size_t off = 0;
    auto alloc = [&](size_t bytes) {
        char* p = ws + off;
        off = (off + bytes + 255) & ~(size_t)255;
        return p;
    };
    __half*       h1   = (__half*)alloc((size_t)N * 16 * 2);
    __half*       X1r  = (__half*)alloc((size_t)N * 16 * 2);
    float*        as1  = (float*)alloc((size_t)N * 4);
    float*        ad1  = (float*)alloc((size_t)N * 4);
    float*        as2  = (float*)alloc((size_t)N * 4);
    float*        ad2  = (float*)alloc((size_t)N * 4);
    int*          rowb = (int*)alloc((size_t)N * 4);
    int*          degb = (int*)alloc((size_t)N * 4);
    uint2*        cw   = (uint2*)alloc((size_t)NBUCK * BSTRIDE * 8);
    uint2*        pk   = (uint2*)alloc((size_t)NBUCK * BSTRIDE * 8);
    int*          gcur = (int*)alloc((size_t)NBUCK * 4);
    float*        va   = (float*)alloc(16 * 4);
    float*        vd   = (float*)alloc(16 * 4);
    float*        Wc   = (float*)alloc(160 * 4);
    float*        bc   = (float*)alloc(10 * 4);
    (void)ws_size;

    // ===== front: layer-1 transform | weight folding + gcur init =====
    front_kernel<<<TB + 1, B, 0, stream>>>(
        x, W1, a1_src, a1_dst, h1, as1, ad1, N, TB,
        W2, a2_src, a2_dst, b2, Wl, bl, va, vd, Wc, bc, gcur, NBUCK);

    // ===== fused single-pass hist + reserve + w1 + scatter =====
    scatter_kernel<<<NBLK, B, 0, stream>>>(ei, E, ET, gcur, pk, NBUCK, as1, ad1);

    // ===== per-bucket LDS counting sort (single pk pass) =====
    bucketsort_kernel<<<NBUCK, 256, 0, stream>>>(pk, gcur, cw, rowb, degb, N);

    // ===== layer 1 agg (streaming staged weights) =====
    gat_agg1_kernel<<<cdiv(N * 16, B), B, 0, stream>>>(rowb, degb, cw, h1, b1, va, vd, X1r, as2, ad2, N);

    // ===== layer 2 agg + folded linear =====
    gat_agg2_kernel<<<cdiv(N * 16, B), B, 0, stream>>>(rowb, degb, cw, as2, ad2, X1r, Wc, bc, out, N);
}